// Round 1
// baseline (149.805 us; speedup 1.0000x reference)
//
#include <hip/hip_runtime.h>
#include <hip/hip_bf16.h>

#define CC   128
#define HH_  64
#define WW_  64
#define BB   8
#define HWSZ (HH_*WW_)      // 4096
#define CHW  (CC*HWSZ)      // 524288
#define BCHW (BB*CHW)       // 4194304
#define PAD  3
#define NP   49

typedef __attribute__((ext_vector_type(8))) short short8;
typedef __attribute__((ext_vector_type(4))) float float4v;

// ============ Kernel 0: W -> bf16 hi/lo split (into d_out scratch) ==========
__global__ __launch_bounds__(256) void prep_w(
    const float* __restrict__ Wq, const float* __restrict__ Wk,
    const float* __restrict__ Wv,
    unsigned short* __restrict__ whi, unsigned short* __restrict__ wlo)
{
    int i = blockIdx.x * 256 + threadIdx.x;          // 0..49151
    const float* src = (i < 16384) ? Wq : (i < 32768 ? Wk : Wv);
    float f = src[i & 16383];
    __hip_bfloat16 h = __float2bfloat16(f);
    float hf = __bfloat162float(h);
    __hip_bfloat16 l = __float2bfloat16(f - hf);
    unsigned short hu, lu;
    __builtin_memcpy(&hu, &h, 2);
    __builtin_memcpy(&lu, &l, 2);
    whi[i] = hu;
    wlo[i] = lu;
}

// ============ Kernel 1: q/k/v GEMM via split-bf16 MFMA (unchanged) ==========
__global__ __launch_bounds__(256, 2) void qkv_mfma(
    const float* __restrict__ x,
    const unsigned short* __restrict__ whi, const unsigned short* __restrict__ wlo,
    const float* __restrict__ bq, const float* __restrict__ bk,
    const float* __restrict__ bv, float* __restrict__ qkv)
{
    __shared__ unsigned short xT[2][128][136];   // [hi/lo][px][c], 69632 B
    const int proj = blockIdx.y;
    const int n0g  = blockIdx.x << 7;
    const int b    = n0g >> 12;
    const int npx  = n0g & 4095;
    const int tid  = threadIdx.x;
    const int lane = tid & 63;
    const int wv   = tid >> 6;
    const int wm   = wv & 1, wn = wv >> 1;

    const float* xb = x + (size_t)b*CHW + npx;
    #pragma unroll
    for (int it = 0; it < 16; ++it) {
        int f  = tid + (it << 8);       // 0..4095
        int c  = f >> 5;                // 0..127
        int p4 = (f & 31) << 2;         // px quad
        float4 v = *(const float4*)&xb[(size_t)c*HWSZ + p4];
        float vv[4] = {v.x, v.y, v.z, v.w};
        #pragma unroll
        for (int u = 0; u < 4; ++u) {
            __hip_bfloat16 h = __float2bfloat16(vv[u]);
            float hf = __bfloat162float(h);
            __hip_bfloat16 l = __float2bfloat16(vv[u] - hf);
            unsigned short hu, lu;
            __builtin_memcpy(&hu, &h, 2);
            __builtin_memcpy(&lu, &l, 2);
            xT[0][p4 + u][c] = hu;
            xT[1][p4 + u][c] = lu;
        }
    }

    const float* Bp = (proj == 0) ? bq : (proj == 1 ? bk : bv);
    const int q4 = lane >> 4;
    float4v acc[4][4];
    #pragma unroll
    for (int sm = 0; sm < 4; ++sm) {
        const int mb = wm*64 + sm*16 + q4*4;
        float4v bi;
        bi[0] = Bp[mb+0]; bi[1] = Bp[mb+1]; bi[2] = Bp[mb+2]; bi[3] = Bp[mb+3];
        #pragma unroll
        for (int sn = 0; sn < 4; ++sn) acc[sm][sn] = bi;
    }

    __syncthreads();

    const unsigned short* Wh = whi + (size_t)proj*16384;
    const unsigned short* Wl = wlo + (size_t)proj*16384;
    const int kq8  = q4 << 3;
    const int mrow = lane & 15;

    for (int pass = 0; pass < 3; ++pass) {
        const unsigned short* Wp = (pass == 2) ? Wl : Wh;
        const int xi = (pass == 1) ? 1 : 0;
        #pragma unroll
        for (int kc = 0; kc < 4; ++kc) {
            const int kb = kc << 5;
            short8 a[4], bf[4];
            #pragma unroll
            for (int sm = 0; sm < 4; ++sm) {
                const int m = wm*64 + sm*16 + mrow;
                a[sm] = *(const short8*)&Wp[(size_t)m*CC + kb + kq8];
            }
            #pragma unroll
            for (int sn = 0; sn < 4; ++sn) {
                const int n = wn*64 + sn*16 + mrow;
                bf[sn] = *(const short8*)&xT[xi][n][kb + kq8];
            }
            #pragma unroll
            for (int sm = 0; sm < 4; ++sm)
                #pragma unroll
                for (int sn = 0; sn < 4; ++sn)
                    acc[sm][sn] = __builtin_amdgcn_mfma_f32_16x16x32_bf16(
                        a[sm], bf[sn], acc[sm][sn], 0, 0, 0);
        }
    }

    float* op = qkv + (size_t)proj*BCHW + (size_t)b*CHW + npx;
    #pragma unroll
    for (int sm = 0; sm < 4; ++sm) {
        const int mb = wm*64 + sm*16 + q4*4;
        #pragma unroll
        for (int sn = 0; sn < 4; ++sn) {
            const int n = wn*64 + sn*16 + mrow;
            #pragma unroll
            for (int r = 0; r < 4; ++r)
                op[(size_t)(mb + r)*HWSZ + n] = acc[sm][sn][r];
        }
    }
}

// ================= Kernel 2: local attention v4 (16-wave blocks) ============
// Block = (b, h0..h0+1), 1024 thr (16 waves), grid 256, XCD swizzle kept.
// Same math / FMA order as v3 (bitwise-identical outputs); per-wave work is
// halved so occupancy doubles (8 -> 16 waves/CU):
//   Phase A: wave s -> (rsel = s>>3 selects q-row h0+rsel, kr = s&7 selects
//     k-row slot). acc[7][4] only. Waves (rsel0,kr7) and (rsel1,kr0) idle.
//   Phase C: wave s -> row h0+rsel, channel pair 2*(s&7) of the 16-ch chunk.
//     a[49] only (halves the VGPR hog that previously forced 98 regs/lane).
__device__ __forceinline__ void load_chunk16(const float* __restrict__ src,
                                             int h0, int c0, float4* stg) {
    const int tid = threadIdx.x;
    #pragma unroll
    for (int i = 0; i < 2; ++i) {
        int f   = tid + (i << 10);          // 0..2047 = 16ch * 8r * 16quads
        int c   = f >> 7;
        int rem = f & 127;
        int r   = rem >> 4;
        int q4  = (rem & 15) << 2;
        int hh  = h0 - PAD + r;
        if ((unsigned)hh < (unsigned)HH_)
            stg[i] = *(const float4*)&src[(size_t)(c0 + c)*HWSZ + hh*WW_ + q4];
        else
            stg[i] = make_float4(0.f, 0.f, 0.f, 0.f);
    }
}

__global__ __launch_bounds__(1024) void locatt(
    const float* __restrict__ qkv, float* __restrict__ out)
{
    // union: phase A k-tile [16][8][72] (36864B) / phase C vT[8][72][17] (39168B)
    __shared__ __align__(16) float smem[8*72*17];   // 9792 floats
    __shared__ float lg[2][NP][64];                 // 25088 B
    __shared__ float dn[2][64];

    const int blk = blockIdx.x;
    const int xs  = blk & 7;
    const int jj  = blk >> 3;
    const int b   = jj >> 2;
    const int h0  = (((xs << 2) | (jj & 3)) << 1);
    const int tid = threadIdx.x;
    const int s   = tid >> 6;      // wave 0..15
    const int lane = tid & 63;
    const int q16  = lane & 15;
    const int csub = lane >> 4;
    const int w4   = q16 << 2;
    const int w    = lane;         // phase C pixel
    const int rsel = s >> 3;       // 0: row h0, 1: row h0+1
    const int kr   = s & 7;        // phase A k-row slot

    const float* qp = qkv + (size_t)b*CHW;
    const float* kp = qkv + (size_t)BCHW + (size_t)b*CHW;
    const float* vp = qkv + (size_t)2*BCHW + (size_t)b*CHW;

    float (*ks)[8][72] = (float(*)[8][72])smem;

    // zero k halo cols (cols 0-3 & 68-71; data stores touch 4..67 only)
    if (tid < 256) {
        int idx = tid & 127;
        int c = idx >> 3, r = idx & 7;
        int col = (tid < 128) ? 0 : 68;
        *(float4*)&ks[c][r][col] = make_float4(0.f, 0.f, 0.f, 0.f);
    }

    // wave validity: row h0 uses slots 0..6, row h0+1 uses slots 1..7
    const bool active = rsel ? (kr >= 1) : (kr < 7);

    float acc[7][4];
    #pragma unroll
    for (int dx = 0; dx < 7; ++dx)
        #pragma unroll
        for (int j = 0; j < 4; ++j) acc[dx][j] = 0.f;

    float4 stg[2];
    load_chunk16(kp, h0, 0, stg);

    // -------- Phase A --------
    for (int ck = 0; ck < 8; ++ck) {
        // store chunk (b128)
        #pragma unroll
        for (int i = 0; i < 2; ++i) {
            int f   = tid + (i << 10);
            int c   = f >> 7;
            int rem = f & 127;
            int r   = rem >> 4;
            int q4  = (rem & 15) << 2;
            *(float4*)&ks[c][r][4 + q4] = stg[i];
        }
        __syncthreads();
        if (ck < 7) load_chunk16(kp, h0, (ck + 1) * 16, stg);

        if (active) {
            const int c0 = ck << 4;
            #pragma unroll
            for (int ci4 = 0; ci4 < 4; ++ci4) {
                const int c = (ci4 << 2) + csub;
                const float* qc = qp + (size_t)(c0 + c)*HWSZ
                                     + (size_t)(h0 + rsel)*WW_ + w4;
                float4 qv  = *(const float4*)qc;
                float4 ka  = *(const float4*)&ks[c][kr][w4];
                float4 kb  = *(const float4*)&ks[c][kr][w4 + 4];
                float4 kc2 = *(const float4*)&ks[c][kr][w4 + 8];
                float kw[12] = {ka.x,ka.y,ka.z,ka.w, kb.x,kb.y,kb.z,kb.w,
                                kc2.x,kc2.y,kc2.z,kc2.w};
                float qa[4] = {qv.x,qv.y,qv.z,qv.w};
                #pragma unroll
                for (int dx = 0; dx < 7; ++dx)
                    #pragma unroll
                    for (int j = 0; j < 4; ++j) {
                        float kv = kw[j + dx + 1];   // spatial w4+j+dx-3
                        acc[dx][j] = fmaf(qa[j], kv, acc[dx][j]);
                    }
            }
        }
        __syncthreads();
    }

    // cross-csub reduce + lg write (active waves only)
    if (active) {
        #pragma unroll
        for (int dx = 0; dx < 7; ++dx)
            #pragma unroll
            for (int j = 0; j < 4; ++j) {
                acc[dx][j] += __shfl_xor(acc[dx][j], 16, 64);
                acc[dx][j] += __shfl_xor(acc[dx][j], 32, 64);
            }
        const int p0 = rsel ? (kr - 1) * 7 : kr * 7;
        #pragma unroll
        for (int dx = 0; dx < 7; ++dx) {
            if ((dx & 3) == csub)
                *(float4*)&lg[rsel][p0 + dx][w4] =
                    make_float4(acc[dx][0], acc[dx][1], acc[dx][2], acc[dx][3]);
        }
    }

    // prefetch v chunk 0: wave s -> channel pair cpl..cpl+1, rows rbase..rbase+3
    const int cpl   = (s & 7) << 1;
    const int rbase = rsel << 2;
    float vreg[8];
    {
        #pragma unroll
        for (int i = 0; i < 8; ++i) {
            int ch = i >> 2;
            int r  = rbase + (i & 3);
            int hh = h0 - PAD + r;
            vreg[i] = ((unsigned)hh < (unsigned)HH_)
                      ? vp[(size_t)(cpl + ch)*HWSZ + hh*WW_ + w] : 0.f;
        }
    }
    __syncthreads();

    // -------- Phase B: two softmaxes (OOB logits exactly 0, included) ------
    if (tid < 128) {
        const int r = tid >> 6, px = tid & 63;
        float tv[NP];
        float m = -1e30f;
        #pragma unroll
        for (int p = 0; p < NP; ++p) { tv[p] = lg[r][p][px]; m = fmaxf(m, tv[p]); }
        float d = 0.f;
        #pragma unroll
        for (int p = 0; p < NP; ++p) {
            float e = __expf(tv[p] - m);
            d += e;
            lg[r][p][px] = e;
        }
        dn[r][px] = 1.f / d;
    } else {
        // zero vT halo cols {0..3, 68..71} x 8r x 16 slots (1024 floats)
        int t = tid - 128;
        for (int i = t; i < 1024; i += 896) {
            int r    = i >> 7;
            int rem  = i & 127;
            int colg = rem >> 4;
            int col  = (colg < 4) ? colg : (64 + colg);
            smem[r*1224 + col*17 + (rem & 15)] = 0.f;
        }
    }
    __syncthreads();

    // -------- Phase C --------
    float a[NP];
    const float sc = dn[rsel][w];
    #pragma unroll
    for (int p = 0; p < NP; ++p) a[p] = lg[rsel][p][w] * sc;

    for (int ck = 0; ck < 8; ++ck) {
        // store vreg -> vT[r][4+w][c]  (stride 17 across lanes: conflict-free)
        #pragma unroll
        for (int i = 0; i < 8; ++i) {
            int ch = i >> 2;
            int r  = rbase + (i & 3);
            smem[r*1224 + (4 + w)*17 + cpl + ch] = vreg[i];
        }
        __syncthreads();
        if (ck < 7) {
            int c0v = (ck + 1) << 4;
            #pragma unroll
            for (int i = 0; i < 8; ++i) {
                int ch = i >> 2;
                int r  = rbase + (i & 3);
                int hh = h0 - PAD + r;
                vreg[i] = ((unsigned)hh < (unsigned)HH_)
                          ? vp[(size_t)(c0v + cpl + ch)*HWSZ + hh*WW_ + w] : 0.f;
            }
        }
        float ya = 0.f, yb = 0.f;
        #pragma unroll
        for (int rl = 0; rl < 7; ++rl) {
            const int r = rl + rsel;   // rsel0: slots 0..6, rsel1: slots 1..7
            const float* vbase = &smem[r*1224 + (1 + w)*17 + cpl];
            #pragma unroll
            for (int dx = 0; dx < 7; ++dx) {
                float va = vbase[17*dx];       // channel cpl
                float vb = vbase[17*dx + 1];   // channel cpl+1 (ds_read2 pair)
                float aw = a[rl*7 + dx];
                ya = fmaf(aw, va, ya);
                yb = fmaf(aw, vb, yb);
            }
        }
        float* op = out + (size_t)b*CHW + (size_t)(ck*16 + cpl)*HWSZ
                        + (size_t)(h0 + rsel)*WW_ + w;
        op[0]    = ya;   // c=cpl,   row h0+rsel
        op[HWSZ] = yb;   // c=cpl+1, row h0+rsel
        __syncthreads();
    }
}

extern "C" void kernel_launch(void* const* d_in, const int* in_sizes, int n_in,
                              void* d_out, int out_size, void* d_ws, size_t ws_size,
                              hipStream_t stream) {
    const float* x  = (const float*)d_in[0];
    const float* Wq = (const float*)d_in[1];
    const float* bq = (const float*)d_in[2];
    const float* Wk = (const float*)d_in[3];
    const float* bk = (const float*)d_in[4];
    const float* Wv = (const float*)d_in[5];
    const float* bv = (const float*)d_in[6];
    float* out = (float*)d_out;
    float* qkv = (float*)d_ws;   // 3*BCHW*4 = 50.3 MB scratch

    // d_out doubles as scratch for bf16 W (196 KB); fully overwritten by
    // locatt afterwards (stream-ordered), safe under re-poisoning.
    unsigned short* whi = (unsigned short*)d_out;
    unsigned short* wlo = whi + 3*16384;

    prep_w  <<<192, 256, 0, stream>>>(Wq, Wk, Wv, whi, wlo);
    qkv_mfma<<<dim3(256, 3), 256, 0, stream>>>(x, whi, wlo, bq, bk, bv, qkv);
    locatt  <<<256, 1024, 0, stream>>>(qkv, out);
}